// Round 3
// baseline (38.094 us; speedup 1.0000x reference)
//
#include <hip/hip_runtime.h>

#define B_ 32
#define PHONE_LEN_ 600
#define T_ 4096
#define H_ 256

typedef float vfloat4 __attribute__((ext_vector_type(4)));

// Kernel 1: per-batch-row inclusive scan of change-flags -> idx[b][t].
// 4 waves (256 threads) per row; each lane owns 16 consecutive elements.
__global__ __launch_bounds__(256) void idx_kernel(const int* __restrict__ align,
                                                  int* __restrict__ idx) {
    const int b = blockIdx.x;
    const int tid = threadIdx.x;             // 0..255
    const int lane = tid & 63;
    const int warp = tid >> 6;               // 0..3
    const int* a = align + (size_t)b * T_;
    const int base = tid * 16;

    __shared__ int wave_tot[4];

    int vals[16];
    int prev = (base == 0) ? 0 : a[base - 1];
    int sum = 0;
#pragma unroll
    for (int i = 0; i < 16; i += 4) {
        int4 v = *reinterpret_cast<const int4*>(a + base + i);
        sum += (v.x != prev); vals[i + 0] = sum; prev = v.x;
        sum += (v.y != prev); vals[i + 1] = sum; prev = v.y;
        sum += (v.z != prev); vals[i + 2] = sum; prev = v.z;
        sum += (v.w != prev); vals[i + 3] = sum; prev = v.w;
    }

    // inclusive wave scan of per-lane totals
    int scan = sum;
#pragma unroll
    for (int off = 1; off < 64; off <<= 1) {
        int n = __shfl_up(scan, off, 64);
        if (lane >= off) scan += n;
    }
    if (lane == 63) wave_tot[warp] = scan;
    __syncthreads();
    int wave_off = 0;
#pragma unroll
    for (int w = 0; w < 4; ++w) wave_off += (w < warp) ? wave_tot[w] : 0;

    const int excl = wave_off + scan - sum;  // exclusive prefix for this thread

    int* o = idx + (size_t)b * T_ + base;
#pragma unroll
    for (int i = 0; i < 16; i += 4) {
        int4 r;
        r.x = vals[i + 0] + excl;
        r.y = vals[i + 1] + excl;
        r.z = vals[i + 2] + excl;
        r.w = vals[i + 3] + excl;
        *reinterpret_cast<int4*>(o + i) = r;
    }
}

// Kernel 2: fused gather + three tiny Linear(1->H) projections.
// 1D grid of 8192 blocks, XCD-swizzled so each XCD owns 4 whole batches
// (per-XCD enc working set = 4 * 600KB = 2.4MB < 4MiB L2).
// Block = 256 threads (4 waves); lane covers H via float4 (64*4 = 256);
// block handles 16 consecutive t (4 t per wave). Non-temporal out stores.
__global__ __launch_bounds__(256) void fuse_kernel(
    const float* __restrict__ enc,    // [B, PHONE_LEN, H]
    const float* __restrict__ pitch,  // [B, T]
    const float* __restrict__ beats,  // [B, T]
    const float* __restrict__ wp, const float* __restrict__ bp,
    const float* __restrict__ wb, const float* __restrict__ bb,
    const float* __restrict__ ws, const float* __restrict__ bs,
    const int* __restrict__ idx,      // [B, T]
    float* __restrict__ out) {        // [B, T, H]
    const int lane = threadIdx.x & 63;
    const int warp = threadIdx.x >> 6;        // 0..3

    // XCD-aware swizzle: blocks dispatch round-robin over 8 XCDs, so
    // bid%8 == XCD id (heuristic; perf-only). Give each XCD 4 batches.
    const int bid = blockIdx.x;               // 0..8191
    const int xcd = bid & 7;
    const int j   = bid >> 3;                 // 0..1023
    const int b   = xcd + 8 * (j >> 8);       // 4 batches per XCD
    const int t0  = (j & 255) * 16;

    const int h4 = lane * 4;

    const float4 w_p = *reinterpret_cast<const float4*>(wp + h4);
    const float4 w_b = *reinterpret_cast<const float4*>(wb + h4);
    const float4 w_s = *reinterpret_cast<const float4*>(ws + h4);
    float4 bsum;
    {
        const float4 b1 = *reinterpret_cast<const float4*>(bp + h4);
        const float4 b2 = *reinterpret_cast<const float4*>(bb + h4);
        const float4 b3 = *reinterpret_cast<const float4*>(bs + h4);
        bsum.x = b1.x + b2.x + b3.x;
        bsum.y = b1.y + b2.y + b3.y;
        bsum.z = b1.z + b2.z + b3.z;
        bsum.w = b1.w + b2.w + b3.w;
    }

    const float invT = 1.0f / (float)T_;
#pragma unroll
    for (int tt = warp; tt < 16; tt += 4) {
        const int t = t0 + tt;
        const size_t bt = (size_t)b * T_ + t;
        const int iv = idx[bt];               // wave-uniform scalar
        const float pv = pitch[bt];
        const float bv = beats[bt];
        const float psc = (float)t * invT;

        const float4 e = *reinterpret_cast<const float4*>(
            enc + ((size_t)b * PHONE_LEN_ + iv) * H_ + h4);

        vfloat4 r;
        r.x = e.x + pv * w_p.x + bv * w_b.x + psc * w_s.x + bsum.x;
        r.y = e.y + pv * w_p.y + bv * w_b.y + psc * w_s.y + bsum.y;
        r.z = e.z + pv * w_p.z + bv * w_b.z + psc * w_s.z + bsum.z;
        r.w = e.w + pv * w_p.w + bv * w_b.w + psc * w_s.w + bsum.w;

        __builtin_nontemporal_store(r, reinterpret_cast<vfloat4*>(out + bt * H_ + h4));
    }
}

extern "C" void kernel_launch(void* const* d_in, const int* in_sizes, int n_in,
                              void* d_out, int out_size, void* d_ws, size_t ws_size,
                              hipStream_t stream) {
    const float* enc   = (const float*)d_in[0];
    const float* pitch = (const float*)d_in[1];
    const float* beats = (const float*)d_in[2];
    const float* wp    = (const float*)d_in[3];
    const float* bp    = (const float*)d_in[4];
    const float* wb    = (const float*)d_in[5];
    const float* bb    = (const float*)d_in[6];
    const float* wsp   = (const float*)d_in[7];
    const float* bsp   = (const float*)d_in[8];
    const int*   align = (const int*)d_in[9];

    int* idx = (int*)d_ws;   // B*T*4 = 512 KB scratch

    idx_kernel<<<B_, 256, 0, stream>>>(align, idx);
    fuse_kernel<<<8192, 256, 0, stream>>>(
        enc, pitch, beats, wp, bp, wb, bb, wsp, bsp, idx, (float*)d_out);
}

// Round 4
// 32.179 us; speedup vs baseline: 1.1838x; 1.1838x over previous
//
#include <hip/hip_runtime.h>

#define B_ 32
#define PHONE_LEN_ 600
#define T_ 4096
#define H_ 256
#define TPB_ 64   // t's per block

// Single fused kernel.
// Grid: (T/TPB, B). Block: 256 threads = 4 waves; wave w handles the
// contiguous t-chunk [t0 + w*16, t0 + w*16 + 16); lane covers H via float4.
//
// idx is computed per block WITHOUT a prefix scan over t, exploiting that
// align rows are sorted: idx[t] = (#present values < align[t]) + (align[0]!=0).
// Presence bitmap over the 512 possible values lives in LDS; one block-wide
// prefix sum turns it into a lookup table.
__global__ __launch_bounds__(256) void fuse_kernel(
    const float* __restrict__ enc,    // [B, PHONE_LEN, H]
    const float* __restrict__ pitch,  // [B, T]
    const float* __restrict__ beats,  // [B, T]
    const float* __restrict__ wp, const float* __restrict__ bp,
    const float* __restrict__ wb, const float* __restrict__ bb,
    const float* __restrict__ ws, const float* __restrict__ bs,
    const int* __restrict__ align,    // [B, T] (sorted per row)
    float* __restrict__ out) {        // [B, T, H]
    const int tid  = threadIdx.x;
    const int lane = tid & 63;
    const int warp = tid >> 6;                // 0..3
    const int b  = blockIdx.y;
    const int t0 = blockIdx.x * TPB_;

    __shared__ unsigned char pres[512];
    __shared__ int pref[512];
    __shared__ int wsum[4];

    const int* __restrict__ arow = align + (size_t)b * T_;

    // ---- presence bitmap over the whole row (4096 elems, 16 per thread) ----
    reinterpret_cast<unsigned short*>(pres)[tid] = 0;
    __syncthreads();
#pragma unroll
    for (int i = 0; i < 16; i += 4) {
        int4 v = *reinterpret_cast<const int4*>(arow + tid * 16 + i);
        pres[v.x] = 1; pres[v.y] = 1; pres[v.z] = 1; pres[v.w] = 1;
    }
    __syncthreads();

    // ---- block-wide exclusive prefix sum of presence (2 entries/thread) ----
    const int p0 = pres[2 * tid];
    const int p1 = pres[2 * tid + 1];
    const int s  = p0 + p1;
    int scan = s;
#pragma unroll
    for (int off = 1; off < 64; off <<= 1) {
        int n = __shfl_up(scan, off, 64);
        if (lane >= off) scan += n;
    }
    if (lane == 63) wsum[warp] = scan;
    __syncthreads();
    int woff = 0;
#pragma unroll
    for (int w = 0; w < 4; ++w) woff += (w < warp) ? wsum[w] : 0;
    const int excl = woff + scan - s;         // #present values < 2*tid
    pref[2 * tid]     = excl;
    pref[2 * tid + 1] = excl + p0;
    __syncthreads();

    const int adj = (arow[0] != 0) ? 1 : 0;   // wave-uniform

    // ---- main fused loop ----
    const int h4 = lane * 4;
    const float4 w_p = *reinterpret_cast<const float4*>(wp + h4);
    const float4 w_b = *reinterpret_cast<const float4*>(wb + h4);
    const float4 w_s = *reinterpret_cast<const float4*>(ws + h4);
    float4 bsum;
    {
        const float4 b1 = *reinterpret_cast<const float4*>(bp + h4);
        const float4 b2 = *reinterpret_cast<const float4*>(bb + h4);
        const float4 b3 = *reinterpret_cast<const float4*>(bs + h4);
        bsum.x = b1.x + b2.x + b3.x;
        bsum.y = b1.y + b2.y + b3.y;
        bsum.z = b1.z + b2.z + b3.z;
        bsum.w = b1.w + b2.w + b3.w;
    }

    const float invT = 1.0f / (float)T_;
    const int tw = t0 + warp * 16;            // this wave's 16 consecutive t
#pragma unroll
    for (int tt = 0; tt < 16; ++tt) {
        const int t = tw + tt;
        const size_t bt = (size_t)b * T_ + t;
        const int iv = pref[arow[t]] + adj;   // encoder row index
        const float pv = pitch[bt];
        const float bv = beats[bt];
        const float psc = (float)t * invT;

        const float4 e = *reinterpret_cast<const float4*>(
            enc + ((size_t)b * PHONE_LEN_ + iv) * H_ + h4);

        float4 r;
        r.x = e.x + pv * w_p.x + bv * w_b.x + psc * w_s.x + bsum.x;
        r.y = e.y + pv * w_p.y + bv * w_b.y + psc * w_s.y + bsum.y;
        r.z = e.z + pv * w_p.z + bv * w_b.z + psc * w_s.z + bsum.z;
        r.w = e.w + pv * w_p.w + bv * w_b.w + psc * w_s.w + bsum.w;

        *reinterpret_cast<float4*>(out + bt * H_ + h4) = r;
    }
}

extern "C" void kernel_launch(void* const* d_in, const int* in_sizes, int n_in,
                              void* d_out, int out_size, void* d_ws, size_t ws_size,
                              hipStream_t stream) {
    const float* enc   = (const float*)d_in[0];
    const float* pitch = (const float*)d_in[1];
    const float* beats = (const float*)d_in[2];
    const float* wp    = (const float*)d_in[3];
    const float* bp    = (const float*)d_in[4];
    const float* wb    = (const float*)d_in[5];
    const float* bb    = (const float*)d_in[6];
    const float* wsp   = (const float*)d_in[7];
    const float* bsp   = (const float*)d_in[8];
    const int*   align = (const int*)d_in[9];

    fuse_kernel<<<dim3(T_ / TPB_, B_), 256, 0, stream>>>(
        enc, pitch, beats, wp, bp, wb, bb, wsp, bsp, align, (float*)d_out);
}

// Round 5
// 30.633 us; speedup vs baseline: 1.2435x; 1.0505x over previous
//
#include <hip/hip_runtime.h>

#define B_ 32
#define PHONE_LEN_ 600
#define T_ 4096
#define H_ 256
#define TPB_ 64   // t's per block

typedef float vfloat4 __attribute__((ext_vector_type(4)));

// Single fused kernel. Identical to R4 winner except: out stores are
// non-temporal (evict-first in L2) so the 128MB write stream stops
// thrashing the enc/align working set out of L2. (R3 tested NT+swizzle
// together and regressed; this isolates NT.)
//
// Grid: (T/TPB, B). Block: 256 threads = 4 waves; wave w handles the
// contiguous t-chunk [t0 + w*16, t0 + w*16 + 16); lane covers H via float4.
//
// idx is computed per block WITHOUT a prefix scan over t, exploiting that
// align rows are sorted: idx[t] = (#present values < align[t]) + (align[0]!=0).
__global__ __launch_bounds__(256) void fuse_kernel(
    const float* __restrict__ enc,    // [B, PHONE_LEN, H]
    const float* __restrict__ pitch,  // [B, T]
    const float* __restrict__ beats,  // [B, T]
    const float* __restrict__ wp, const float* __restrict__ bp,
    const float* __restrict__ wb, const float* __restrict__ bb,
    const float* __restrict__ ws, const float* __restrict__ bs,
    const int* __restrict__ align,    // [B, T] (sorted per row)
    float* __restrict__ out) {        // [B, T, H]
    const int tid  = threadIdx.x;
    const int lane = tid & 63;
    const int warp = tid >> 6;                // 0..3
    const int b  = blockIdx.y;
    const int t0 = blockIdx.x * TPB_;

    __shared__ unsigned char pres[512];
    __shared__ int pref[512];
    __shared__ int wsum[4];

    const int* __restrict__ arow = align + (size_t)b * T_;

    // ---- presence bitmap over the whole row (4096 elems, 16 per thread) ----
    reinterpret_cast<unsigned short*>(pres)[tid] = 0;
    __syncthreads();
#pragma unroll
    for (int i = 0; i < 16; i += 4) {
        int4 v = *reinterpret_cast<const int4*>(arow + tid * 16 + i);
        pres[v.x] = 1; pres[v.y] = 1; pres[v.z] = 1; pres[v.w] = 1;
    }
    __syncthreads();

    // ---- block-wide exclusive prefix sum of presence (2 entries/thread) ----
    const int p0 = pres[2 * tid];
    const int p1 = pres[2 * tid + 1];
    const int s  = p0 + p1;
    int scan = s;
#pragma unroll
    for (int off = 1; off < 64; off <<= 1) {
        int n = __shfl_up(scan, off, 64);
        if (lane >= off) scan += n;
    }
    if (lane == 63) wsum[warp] = scan;
    __syncthreads();
    int woff = 0;
#pragma unroll
    for (int w = 0; w < 4; ++w) woff += (w < warp) ? wsum[w] : 0;
    const int excl = woff + scan - s;         // #present values < 2*tid
    pref[2 * tid]     = excl;
    pref[2 * tid + 1] = excl + p0;
    __syncthreads();

    const int adj = (arow[0] != 0) ? 1 : 0;   // wave-uniform

    // ---- main fused loop ----
    const int h4 = lane * 4;
    const float4 w_p = *reinterpret_cast<const float4*>(wp + h4);
    const float4 w_b = *reinterpret_cast<const float4*>(wb + h4);
    const float4 w_s = *reinterpret_cast<const float4*>(ws + h4);
    float4 bsum;
    {
        const float4 b1 = *reinterpret_cast<const float4*>(bp + h4);
        const float4 b2 = *reinterpret_cast<const float4*>(bb + h4);
        const float4 b3 = *reinterpret_cast<const float4*>(bs + h4);
        bsum.x = b1.x + b2.x + b3.x;
        bsum.y = b1.y + b2.y + b3.y;
        bsum.z = b1.z + b2.z + b3.z;
        bsum.w = b1.w + b2.w + b3.w;
    }

    const float invT = 1.0f / (float)T_;
    const int tw = t0 + warp * 16;            // this wave's 16 consecutive t
#pragma unroll
    for (int tt = 0; tt < 16; ++tt) {
        const int t = tw + tt;
        const size_t bt = (size_t)b * T_ + t;
        const int iv = pref[arow[t]] + adj;   // encoder row index
        const float pv = pitch[bt];
        const float bv = beats[bt];
        const float psc = (float)t * invT;

        const float4 e = *reinterpret_cast<const float4*>(
            enc + ((size_t)b * PHONE_LEN_ + iv) * H_ + h4);

        vfloat4 r;
        r.x = e.x + pv * w_p.x + bv * w_b.x + psc * w_s.x + bsum.x;
        r.y = e.y + pv * w_p.y + bv * w_b.y + psc * w_s.y + bsum.y;
        r.z = e.z + pv * w_p.z + bv * w_b.z + psc * w_s.z + bsum.z;
        r.w = e.w + pv * w_p.w + bv * w_b.w + psc * w_s.w + bsum.w;

        __builtin_nontemporal_store(r, reinterpret_cast<vfloat4*>(out + bt * H_ + h4));
    }
}

extern "C" void kernel_launch(void* const* d_in, const int* in_sizes, int n_in,
                              void* d_out, int out_size, void* d_ws, size_t ws_size,
                              hipStream_t stream) {
    const float* enc   = (const float*)d_in[0];
    const float* pitch = (const float*)d_in[1];
    const float* beats = (const float*)d_in[2];
    const float* wp    = (const float*)d_in[3];
    const float* bp    = (const float*)d_in[4];
    const float* wb    = (const float*)d_in[5];
    const float* bb    = (const float*)d_in[6];
    const float* wsp   = (const float*)d_in[7];
    const float* bsp   = (const float*)d_in[8];
    const int*   align = (const int*)d_in[9];

    fuse_kernel<<<dim3(T_ / TPB_, B_), 256, 0, stream>>>(
        enc, pitch, beats, wp, bp, wb, bb, wsp, bsp, align, (float*)d_out);
}

// Round 6
// 28.308 us; speedup vs baseline: 1.3457x; 1.0821x over previous
//
#include <hip/hip_runtime.h>

#define B_ 32
#define PHONE_LEN_ 600
#define T_ 4096
#define H_ 256
#define TPB_ 128   // t's per block (4 waves x 32 t)

typedef float vfloat4 __attribute__((ext_vector_type(4)));

// Single fused kernel, R5 winner + :
//  - TPB 64->128 (halves prologue/align-reread overhead)
//  - per-wave scalar preload: lanes 0..31 hold {idx,pitch}, lanes 32..63 hold
//    beats for the wave's 32 t's; main loop uses readlane -> iv/pv/bv become
//    wave-uniform SGPRs, enc address is scalar-base + lane*16.
//  - non-temporal out stores (R5 proven win).
//
// idx per block without a t-scan, exploiting sorted align rows:
// idx[t] = (#present values < align[t]) + (align[0]!=0).
__global__ __launch_bounds__(256) void fuse_kernel(
    const float* __restrict__ enc,    // [B, PHONE_LEN, H]
    const float* __restrict__ pitch,  // [B, T]
    const float* __restrict__ beats,  // [B, T]
    const float* __restrict__ wp, const float* __restrict__ bp,
    const float* __restrict__ wb, const float* __restrict__ bb,
    const float* __restrict__ ws, const float* __restrict__ bs,
    const int* __restrict__ align,    // [B, T] (sorted per row)
    float* __restrict__ out) {        // [B, T, H]
    const int tid  = threadIdx.x;
    const int lane = tid & 63;
    const int warp = tid >> 6;                // 0..3
    const int b  = blockIdx.y;
    const int t0 = blockIdx.x * TPB_;

    __shared__ unsigned char pres[512];
    __shared__ int pref[512];
    __shared__ int wsum[4];

    const int* __restrict__ arow = align + (size_t)b * T_;

    // ---- presence bitmap over the whole row (4096 elems, 16 per thread) ----
    reinterpret_cast<unsigned short*>(pres)[tid] = 0;
    __syncthreads();
#pragma unroll
    for (int i = 0; i < 16; i += 4) {
        int4 v = *reinterpret_cast<const int4*>(arow + tid * 16 + i);
        pres[v.x] = 1; pres[v.y] = 1; pres[v.z] = 1; pres[v.w] = 1;
    }
    __syncthreads();

    // ---- block-wide exclusive prefix sum of presence (2 entries/thread) ----
    const int p0 = pres[2 * tid];
    const int p1 = pres[2 * tid + 1];
    const int s  = p0 + p1;
    int scan = s;
#pragma unroll
    for (int off = 1; off < 64; off <<= 1) {
        int n = __shfl_up(scan, off, 64);
        if (lane >= off) scan += n;
    }
    if (lane == 63) wsum[warp] = scan;
    __syncthreads();
    int woff = 0;
#pragma unroll
    for (int w = 0; w < 4; ++w) woff += (w < warp) ? wsum[w] : 0;
    const int excl = woff + scan - s;         // #present values < 2*tid
    pref[2 * tid]     = excl;
    pref[2 * tid + 1] = excl + p0;
    __syncthreads();

    const int adj = (arow[0] != 0) ? 1 : 0;

    // ---- per-wave scalar preload ----
    // wave handles t in [tw, tw+32); lane<32: idx & pitch for t=tw+lane,
    // lane>=32: beats for t=tw+lane-32.
    const int tw = t0 + warp * 32;
    const size_t btw = (size_t)b * T_ + tw;

    int   reg_iv;
    float reg_pb;
    if (lane < 32) {
        reg_iv = pref[arow[tw + lane]] + adj;
        reg_pb = pitch[btw + lane];
    } else {
        reg_iv = 0;
        reg_pb = beats[btw + (lane - 32)];
    }

    // ---- weights / fused bias ----
    const int h4 = lane * 4;
    const float4 w_p = *reinterpret_cast<const float4*>(wp + h4);
    const float4 w_b = *reinterpret_cast<const float4*>(wb + h4);
    const float4 w_s = *reinterpret_cast<const float4*>(ws + h4);
    float4 bsum;
    {
        const float4 b1 = *reinterpret_cast<const float4*>(bp + h4);
        const float4 b2 = *reinterpret_cast<const float4*>(bb + h4);
        const float4 b3 = *reinterpret_cast<const float4*>(bs + h4);
        bsum.x = b1.x + b2.x + b3.x;
        bsum.y = b1.y + b2.y + b3.y;
        bsum.z = b1.z + b2.z + b3.z;
        bsum.w = b1.w + b2.w + b3.w;
    }

    const float invT = 1.0f / (float)T_;
    const float* encb = enc + (size_t)b * PHONE_LEN_ * H_;
    float* outb = out + (btw)*H_;

    const int ipb = __float_as_int(reg_pb);
#pragma unroll
    for (int i = 0; i < 32; ++i) {
        const int   iv = __builtin_amdgcn_readlane(reg_iv, i);       // SGPR
        const float pv = __int_as_float(__builtin_amdgcn_readlane(ipb, i));
        const float bv = __int_as_float(__builtin_amdgcn_readlane(ipb, 32 + i));
        const float psc = (float)(tw + i) * invT;

        const float4 e = *reinterpret_cast<const float4*>(encb + iv * H_ + h4);

        vfloat4 r;
        r.x = e.x + pv * w_p.x + bv * w_b.x + psc * w_s.x + bsum.x;
        r.y = e.y + pv * w_p.y + bv * w_b.y + psc * w_s.y + bsum.y;
        r.z = e.z + pv * w_p.z + bv * w_b.z + psc * w_s.z + bsum.z;
        r.w = e.w + pv * w_p.w + bv * w_b.w + psc * w_s.w + bsum.w;

        __builtin_nontemporal_store(r, reinterpret_cast<vfloat4*>(outb + i * H_ + h4));
    }
}

extern "C" void kernel_launch(void* const* d_in, const int* in_sizes, int n_in,
                              void* d_out, int out_size, void* d_ws, size_t ws_size,
                              hipStream_t stream) {
    const float* enc   = (const float*)d_in[0];
    const float* pitch = (const float*)d_in[1];
    const float* beats = (const float*)d_in[2];
    const float* wp    = (const float*)d_in[3];
    const float* bp    = (const float*)d_in[4];
    const float* wb    = (const float*)d_in[5];
    const float* bb    = (const float*)d_in[6];
    const float* wsp   = (const float*)d_in[7];
    const float* bsp   = (const float*)d_in[8];
    const int*   align = (const int*)d_in[9];

    fuse_kernel<<<dim3(T_ / TPB_, B_), 256, 0, stream>>>(
        enc, pitch, beats, wp, bp, wb, bb, wsp, bsp, align, (float*)d_out);
}